// Round 6
// baseline (112.032 us; speedup 1.0000x reference)
//
#include <hip/hip_runtime.h>

// Adaptive Wing loss, reduction='sum', fp32 in/out.
// THETA=0.5, ALPHA=2.1, OMEGA=14.0, EPS=1.0
//   p = 2.1 - target; t = 2^(-p)
//   lt  (diff<0.5): loss = 14*ln(1 + diff^p)
//   ge: loss = A*(diff-0.5) + 14*ln(1+t),  A = 28*p*t/(1+t)
// A(target) and L(target)=14*ln(1+t) are smooth 1-D functions -> quartic fits
// (Newton interpolation at u=0,.25,.5,.75,1; off-node err <= 2.6e-4, budget 0.05).
//
// R2: libm -> native v_exp/v_log (VALUBusy 62->30%).
// R4: strided unroll scattered in-flight set -> reverted (120us).
// R5: depth-2 contiguous unroll -> 97.4us.
// R6: poly A/L (5->3 trans, no rcp), depth-4 contiguous unroll (8 hoisted
//     loads, wave tiles 4KB/array), fused finish via memset+per-block atomic.

#define LN2_X14 9.704060527839234f  // 14 * ln(2)

__device__ __forceinline__ float awl_elem(float x, float tg) {
    float diff = fabsf(tg - x);
    float p = 2.1f - tg;
    // diff^p = 2^(p*log2(diff)); diff==0 -> -inf -> exp2=0 -> log2(1)=0. OK.
    float q  = __builtin_amdgcn_exp2f(p * __builtin_amdgcn_logf(diff));
    float nl = LN2_X14 * __builtin_amdgcn_logf(1.0f + q);
    // ge-branch coefficients: quartic fits in u=target
    float A = fmaf(fmaf(fmaf(fmaf(-0.0054016f, tg, -0.6702400f), tg,
                             -1.5973632f), tg, 0.9491764f), tg, 11.1215496f);
    float L = fmaf(fmaf(fmaf(fmaf(-0.0032405f, tg, 0.0785600f), tg,
                             0.5144176f), tg, 1.8354348f), tg, 2.9352736f);
    float lin = fmaf(A, diff - 0.5f, L);
    return diff < 0.5f ? nl : lin;
}

__device__ __forceinline__ float awl_quad(float4 a, float4 b) {
    return (awl_elem(a.x, b.x) + awl_elem(a.y, b.y))
         + (awl_elem(a.z, b.z) + awl_elem(a.w, b.w));
}

__global__ __launch_bounds__(256) void awl_sum(
    const float4* __restrict__ x, const float4* __restrict__ tg,
    float* __restrict__ out, int n4)
{
    int tid    = blockIdx.x * blockDim.x + threadIdx.x;
    int stride = gridDim.x * blockDim.x;
    int lane   = threadIdx.x & 63;
    int wbase  = ((tid >> 6) << 8) + lane;   // wave tiles 256 contiguous float4s
    int step   = stride << 2;                // depth-4
    float acc = 0.0f;

    int s = 0;
    for (; s + step <= n4; s += step) {
        int i0 = s + wbase;
        float4 a0 = x[i0];
        float4 a1 = x[i0 + 64];
        float4 a2 = x[i0 + 128];
        float4 a3 = x[i0 + 192];
        float4 b0 = tg[i0];
        float4 b1 = tg[i0 + 64];
        float4 b2 = tg[i0 + 128];
        float4 b3 = tg[i0 + 192];
        acc += awl_quad(a0, b0);
        acc += awl_quad(a1, b1);
        acc += awl_quad(a2, b2);
        acc += awl_quad(a3, b3);
    }
    // generic tail (not hit when n4 % step == 0, as here)
    for (int i = s + tid; i < n4; i += stride)
        acc += awl_quad(x[i], tg[i]);

    // wave-64 reduce
    #pragma unroll
    for (int off = 32; off > 0; off >>= 1)
        acc += __shfl_down(acc, off, 64);
    __shared__ float ws[4];
    int wid = threadIdx.x >> 6;
    if (lane == 0) ws[wid] = acc;
    __syncthreads();
    if (threadIdx.x == 0)
        atomicAdd(out, (ws[0] + ws[1]) + (ws[2] + ws[3]));
}

extern "C" void kernel_launch(void* const* d_in, const int* in_sizes, int n_in,
                              void* d_out, int out_size, void* d_ws, size_t ws_size,
                              hipStream_t stream) {
    const float* x  = (const float*)d_in[0];
    const float* tg = (const float*)d_in[1];
    float* out = (float*)d_out;

    long long n = (long long)in_sizes[0];   // 67,108,864 (divisible by 4)
    int n4 = (int)(n / 4);

    int nblk = 2048;                         // 8 blocks/CU -> 32 waves/CU

    hipMemsetAsync(out, 0, sizeof(float) * (out_size > 0 ? out_size : 1), stream);
    awl_sum<<<nblk, 256, 0, stream>>>((const float4*)x, (const float4*)tg, out, n4);
}

// Round 7
// 101.490 us; speedup vs baseline: 1.1039x; 1.1039x over previous
//
#include <hip/hip_runtime.h>

// Adaptive Wing loss, reduction='sum', fp32 in/out.
// THETA=0.5, ALPHA=2.1, OMEGA=14.0, EPS=1.0
//   p = 2.1 - target; t = 2^(-p)
//   lt  (diff<0.5): loss = 14*ln(1 + diff^p)
//   ge: loss = A*(diff-0.5) + 14*ln(1+t),  A = 28*p*t/(1+t)
// A(target), L(target)=14*ln(1+t) replaced by quartic Horner fits
// (off-node err <= 2.6e-4; threshold is ~2% of a 1.7e8 sum -> huge headroom).
//
// R2: libm -> native v_exp/v_log (VALUBusy 62->30%).
// R4: strided unroll scattered the in-flight set -> 120us. Reverted.
// R5: depth-2 contiguous unroll -> 97.4us (VGPR 32: 4 loads in flight).
// R6: poly + depth-4: compiler SANK the hoisted loads (VGPR 20) -> 112us.
// R7: depth-2 + poly + software pipeline with sched_barrier(0) pinning the
//     next-tile loads ahead of current-tile compute (scheduler can't sink).

#define LN2_X14 9.704060527839234f  // 14 * ln(2)

__device__ __forceinline__ float awl_elem(float x, float tg) {
    float diff = fabsf(tg - x);
    float p = 2.1f - tg;
    // diff^p = 2^(p*log2(diff)); diff==0 -> -inf -> exp2=0 -> log2(1)=0. OK.
    float q  = __builtin_amdgcn_exp2f(p * __builtin_amdgcn_logf(diff));
    float nl = LN2_X14 * __builtin_amdgcn_logf(1.0f + q);
    // ge-branch coefficients: quartic fits in target
    float A = fmaf(fmaf(fmaf(fmaf(-0.0054016f, tg, -0.6702400f), tg,
                             -1.5973632f), tg, 0.9491764f), tg, 11.1215496f);
    float L = fmaf(fmaf(fmaf(fmaf(-0.0032405f, tg, 0.0785600f), tg,
                             0.5144176f), tg, 1.8354348f), tg, 2.9352736f);
    float lin = fmaf(A, diff - 0.5f, L);
    return diff < 0.5f ? nl : lin;
}

__device__ __forceinline__ float awl_quad(float4 a, float4 b) {
    return (awl_elem(a.x, b.x) + awl_elem(a.y, b.y))
         + (awl_elem(a.z, b.z) + awl_elem(a.w, b.w));
}

__global__ __launch_bounds__(256) void awl_sum(
    const float4* __restrict__ x, const float4* __restrict__ tg,
    float* __restrict__ out, int n4)
{
    int tid    = blockIdx.x * blockDim.x + threadIdx.x;
    int stride = gridDim.x * blockDim.x;
    int lane   = threadIdx.x & 63;
    int wbase  = ((tid >> 6) << 7) + lane;   // wave tiles 128 contiguous float4s
    int step   = stride << 1;                // depth-2
    float acc  = 0.0f;

    int nfull = n4 / step;                   // full pipelined tiles
    if (nfull > 0) {
        int i = wbase;
        float4 a0 = x[i], a1 = x[i + 64];
        float4 b0 = tg[i], b1 = tg[i + 64];
        for (int it = 0; it < nfull - 1; ++it) {
            int j = i + step;
            float4 na0 = x[j],  na1 = x[j + 64];
            float4 nb0 = tg[j], nb1 = tg[j + 64];
            __builtin_amdgcn_sched_barrier(0);   // pin: next loads issued first
            acc += awl_quad(a0, b0);
            acc += awl_quad(a1, b1);
            a0 = na0; a1 = na1; b0 = nb0; b1 = nb1;
            i = j;
        }
        acc += awl_quad(a0, b0);
        acc += awl_quad(a1, b1);
    }
    // generic tail (empty here: n4 % step == 0)
    for (int j = nfull * step + tid; j < n4; j += stride)
        acc += awl_quad(x[j], tg[j]);

    // wave-64 reduce
    #pragma unroll
    for (int off = 32; off > 0; off >>= 1)
        acc += __shfl_down(acc, off, 64);
    __shared__ float ws[4];
    int wid = threadIdx.x >> 6;
    if (lane == 0) ws[wid] = acc;
    __syncthreads();
    if (threadIdx.x == 0)
        atomicAdd(out, (ws[0] + ws[1]) + (ws[2] + ws[3]));
}

extern "C" void kernel_launch(void* const* d_in, const int* in_sizes, int n_in,
                              void* d_out, int out_size, void* d_ws, size_t ws_size,
                              hipStream_t stream) {
    const float* x  = (const float*)d_in[0];
    const float* tg = (const float*)d_in[1];
    float* out = (float*)d_out;

    long long n = (long long)in_sizes[0];   // 67,108,864 (divisible by 4)
    int n4 = (int)(n / 4);

    int nblk = 2048;                         // 8 blocks/CU -> 32 waves/CU

    hipMemsetAsync(out, 0, sizeof(float) * (out_size > 0 ? out_size : 1), stream);
    awl_sum<<<nblk, 256, 0, stream>>>((const float4*)x, (const float4*)tg, out, n4);
}